// Round 12
// baseline (230.480 us; speedup 1.0000x reference)
//
#include <hip/hip_runtime.h>
#include <math.h>

// NoisyTopKGating: out[N,64] = scatter(softmax(top2(x@W^T + b + noise)))
// N=131072, D=1024, E=64, K=2, NOISE_STD=1.0
//
// Round 12: wave-private barrier-free streaming. R4-R11 invariant: 4 waves
// lock-stepped per block -> only 2 independent HBM streams per CU (the 6.3
// TB/s copy ubench has ~32, barrier-free). This round: each wave owns 32 rows
// x 64 experts with a PRIVATE double-buffered LDS slice (2x8KB) and a private
// pipeline: STAGE(c+1) [8x global_load_lds, 256B runs] -> s_waitcnt vmcnt(8)
// (self-sync; ZERO s_barrier in the kernel) -> COMPUTE(c) -> WPRE(c+1) (W
// frags -> 16 int4 regs from L2-resident frag-major image; in-order issue
// makes the reg WAR safe). 8 independent streams/CU, 64KB DMA in flight.
// Per-block k-phase rotation kept (R7). Epilogue = R5's proven in-register
// butterfly top-3 (no cross-wave data). logits = xh*wh + xh*wl + xl*wh
// (err ~4e-6 << TAU); fp64 repair pass for gap(#2,#3) < TAU (rounds 3-11).

#define NEXP   64
#define BLOCK  256
#define TILE_M 128       // 32 rows per wave
#define DFIX   1024
#define KCF    64        // K floats per chunk -> 256 B per row per visit
#define NCH    16        // DFIX / KCF
#define WCHB   8192      // wave chunk: 32 rows x 256 B
#define TAU    1e-3f
#define CAP    4096
#define WS_W_OFF 32768   // frag-major W image at d_ws + 32 KB

typedef __attribute__((ext_vector_type(8)))  short bf16x8;
typedef __attribute__((ext_vector_type(16))) float f32x16;

__device__ __forceinline__ bool beats(float v, int e, float vo, int eo) {
    // jax.lax.top_k ordering: higher value wins, lower index on tie
    return (v > vo) || (v == vo && e < eo);
}

// Split two fp32 into packed bf16-hi pair and bf16-lo (residual) pair, by truncation.
__device__ __forceinline__ void split2(float f0, float f1, unsigned int& hi, unsigned int& lo) {
    unsigned int u0 = __float_as_uint(f0), u1 = __float_as_uint(f1);
    unsigned int h0 = u0 & 0xFFFF0000u,  h1 = u1 & 0xFFFF0000u;
    float l0 = f0 - __uint_as_float(h0);
    float l1 = f1 - __uint_as_float(h1);
    hi = (u0 >> 16) | h1;
    lo = (__float_as_uint(l0) >> 16) | (__float_as_uint(l1) & 0xFFFF0000u);
}

__device__ __forceinline__ void gl_lds16(const void* g, void* l) {
    __builtin_amdgcn_global_load_lds((const __attribute__((address_space(1))) void*)g,
                                     (__attribute__((address_space(3))) void*)l,
                                     16, 0, 0);
}

// W (64x1024 fp32) -> frag-major bf16 hi/lo image (256 KB):
// frag f = kk*4 + g*2 + h (kk = k-step 0..63, g = expert-half, h: 0=hi 1=lo),
// lane l of frag f holds W[e = g*32 + (l&31)][k = kk*16 + (l>>5)*8 .. +8] (16B).
__global__ void convW_kernel(const float* __restrict__ W, char* __restrict__ wsW) {
    const int e = blockIdx.x;        // 0..63
    const int t = threadIdx.x;       // 0..127 = global k-octet
    const float* wp = W + e * DFIX + t * 8;
    float4 a  = *(const float4*)wp;
    float4 bq = *(const float4*)(wp + 4);
    unsigned int h[4], l[4];
    split2(a.x,  a.y,  h[0], l[0]);
    split2(a.z,  a.w,  h[1], l[1]);
    split2(bq.x, bq.y, h[2], l[2]);
    split2(bq.z, bq.w, h[3], l[3]);
    const int kk   = t >> 1;         // k-step 0..63
    const int lh   = t & 1;          // k-octet within k-step
    const int lane = lh * 32 + (e & 31);
    const int g    = e >> 5;
    char* base = wsW + (size_t)(kk * 4 + g * 2) * 1024 + lane * 16;
    *(uint4*)(base)        = make_uint4(h[0], h[1], h[2], h[3]);  // h=0 (hi)
    *(uint4*)(base + 1024) = make_uint4(l[0], l[1], l[2], l[3]);  // h=1 (lo)
}

__global__ __launch_bounds__(BLOCK, 2)
void gate_mfma(const float* __restrict__ x, const float* __restrict__ bvec,
               const float* __restrict__ noise, const char* __restrict__ wsW,
               float* __restrict__ out, unsigned int* __restrict__ flags) {
    __shared__ __align__(16) char lds[4 * 2 * WCHB];   // 64 KB -> 2 blocks/CU

    const int tid  = threadIdx.x;
    const int wv   = tid >> 6;       // wave 0..3 -> rows [32wv, 32wv+32)
    const int lane = tid & 63;
    const int e0   = lane & 31;      // A-row within wave / expert col in half
    const int lh   = lane >> 5;      // k-octet half selector
    const int blkRow0 = blockIdx.x * TILE_M;
    const int rowBase = blkRow0 + wv * 32;
    const int phase   = blockIdx.x & (NCH - 1);   // k-phase rotation (R7)
    char* wb0 = lds + wv * (2 * WCHB);            // wave-private 16 KB slice

    f32x16 acc0 = (f32x16)0.0f;      // experts 0..31
    f32x16 acc1 = (f32x16)0.0f;      // experts 32..63

    // STAGE chunk gc (256B per row, this wave's 32 rows) into private buf:
    // 8 gl_lds16; slot s (0..511) -> row = s>>4, seg16 = s&15; source seg is
    // XOR-permuted (seg ^ (row&15)) so the COMPUTE ds_read_b128 is ~2-way
    // bank-aliased (free, m136). Linear LDS dest (rule #21).
    auto STAGE = [&](int gc, int buf) {
        char* xb = wb0 + buf * WCHB;
        #pragma unroll
        for (int i = 0; i < 8; i++) {
            const int s   = i * 64 + lane;            // 16B-slot id
            const int row = s >> 4;                   // 0..31
            const int seg = (s & 15) ^ (row & 15);
            const char* gp = (const char*)(x + (size_t)(rowBase + row) * DFIX)
                             + (size_t)gc * 256 + seg * 16;
            gl_lds16(gp, xb + (size_t)(i * 64) * 16); // +lane*16 by HW
        }
    };

    // W frags for chunk gc -> 16 int4 regs (4 ksteps x {g0hi,g0lo,g1hi,g1lo}).
    int4 wreg[16];
    auto WPRE = [&](int gc) {
        #pragma unroll
        for (int ks = 0; ks < 4; ks++) {
            const char* fb = wsW + (size_t)((gc * 4 + ks) * 4) * 1024 + lane * 16;
            wreg[ks * 4 + 0] = *(const int4*)(fb);          // g0 hi
            wreg[ks * 4 + 1] = *(const int4*)(fb + 1024);   // g0 lo
            wreg[ks * 4 + 2] = *(const int4*)(fb + 2048);   // g1 hi
            wreg[ks * 4 + 3] = *(const int4*)(fb + 3072);   // g1 lo
        }
    };

    auto COMPUTE = [&](int buf) {
        const char* xb = wb0 + buf * WCHB;
        #pragma unroll
        for (int ks = 0; ks < 4; ks++) {
            const int g0 = ks * 4 + lh * 2;           // seg16 wanted
            const int4 xq0 = *(const int4*)(xb + e0 * 256 + ((g0    ) ^ (e0 & 15)) * 16);
            const int4 xq1 = *(const int4*)(xb + e0 * 256 + ((g0 + 1) ^ (e0 & 15)) * 16);
            const float4 xa = *(const float4*)&xq0;
            const float4 xc = *(const float4*)&xq1;
            union { bf16x8 v; unsigned int u[4]; } ah, al;
            split2(xa.x, xa.y, ah.u[0], al.u[0]);
            split2(xa.z, xa.w, ah.u[1], al.u[1]);
            split2(xc.x, xc.y, ah.u[2], al.u[2]);
            split2(xc.z, xc.w, ah.u[3], al.u[3]);
            union { bf16x8 v; int4 q; } b0h, b0l, b1h, b1l;
            b0h.q = wreg[ks * 4 + 0];
            b0l.q = wreg[ks * 4 + 1];
            b1h.q = wreg[ks * 4 + 2];
            b1l.q = wreg[ks * 4 + 3];
            acc0 = __builtin_amdgcn_mfma_f32_32x32x16_bf16(ah.v, b0h.v, acc0, 0, 0, 0);
            acc1 = __builtin_amdgcn_mfma_f32_32x32x16_bf16(ah.v, b1h.v, acc1, 0, 0, 0);
            acc0 = __builtin_amdgcn_mfma_f32_32x32x16_bf16(ah.v, b0l.v, acc0, 0, 0, 0);
            acc1 = __builtin_amdgcn_mfma_f32_32x32x16_bf16(ah.v, b1l.v, acc1, 0, 0, 0);
            acc0 = __builtin_amdgcn_mfma_f32_32x32x16_bf16(al.v, b0h.v, acc0, 0, 0, 0);
            acc1 = __builtin_amdgcn_mfma_f32_32x32x16_bf16(al.v, b1h.v, acc1, 0, 0, 0);
        }
    };

    // Wave-private pipeline, no s_barrier anywhere. vmcnt(8): at that point the
    // newest 8 outstanding VMEM ops are STAGE(c+1) -> STAGE(c)+WPRE(c) landed.
    STAGE(phase, 0);
    WPRE(phase);
    #pragma unroll 1
    for (int c = 0; c < NCH; c++) {
        const int gcn = (c + 1 + phase) & (NCH - 1);
        if (c < NCH - 1) {
            STAGE(gcn, (c + 1) & 1);
            asm volatile("s_waitcnt vmcnt(8)" ::: "memory");
        } else {
            asm volatile("s_waitcnt vmcnt(0)" ::: "memory");
        }
        __builtin_amdgcn_sched_barrier(0);            // rule #18: pin reads after wait
        COMPUTE(c & 1);
        if (c < NCH - 1) WPRE(gcn);                   // reg WAR safe: in-order issue
    }

    // ---- Epilogue (R5-proven, fully in-wave): per row top-3 across the two
    // acc halves + 32-lane butterfly; softmax; coalesced float2 stores. ----
    // C layout (verified m74/m101 + rounds 3-11): col = lane&31,
    // row = (reg&3) + 8*(reg>>2) + 4*lh.
    const float bb0 = bvec[e0], bb1 = bvec[e0 + 32];
    #pragma unroll
    for (int q = 0; q < 4; q++) {
        #pragma unroll
        for (int j = 0; j < 4; j++) {
            const int reg = q * 4 + j;
            const int r = rowBase + j + 8 * q + 4 * lh;
            const float n0 = noise[(size_t)r * NEXP + e0];
            const float n1 = noise[(size_t)r * NEXP + e0 + 32];
            const float v0 = (acc0[reg] + bb0) + n0;   // ref order: (dot + b) + noise
            const float v1 = (acc1[reg] + bb1) + n1;

            float v1m, v2m, v3m = -1e30f; int e1m, e2m;
            if (beats(v0, e0, v1, e0 + 32)) { v1m = v0; e1m = e0;      v2m = v1; e2m = e0 + 32; }
            else                            { v1m = v1; e1m = e0 + 32; v2m = v0; e2m = e0;      }
            #pragma unroll
            for (int d = 1; d < 32; d <<= 1) {         // butterfly within 32-lane half
                float ov1 = __shfl_xor(v1m, d); int oe1 = __shfl_xor(e1m, d);
                float ov2 = __shfl_xor(v2m, d); int oe2 = __shfl_xor(e2m, d);
                float ov3 = __shfl_xor(v3m, d);
                bool  aw  = beats(v1m, e1m, ov1, oe1);
                float a1v = aw ? v1m : ov1; int a1e = aw ? e1m : oe1;
                float b1v = aw ? ov1 : v1m; int b1e = aw ? oe1 : e1m;
                float a2v = aw ? v2m : ov2; int a2e = aw ? e2m : oe2;
                float b2v = aw ? ov2 : v2m;
                float a3v = aw ? v3m : ov3;
                bool  s2  = beats(a2v, a2e, b1v, b1e);
                v1m = a1v; e1m = a1e;
                v2m = s2 ? a2v : b1v; e2m = s2 ? a2e : b1e;
                v3m = s2 ? fmaxf(a3v, b1v) : fmaxf(a2v, b2v);
            }
            const float t   = __expf(v2m - v1m);
            const float inv = 1.0f / (1.0f + t);
            const float w1  = inv, w2 = t * inv;

            if (e0 == 0 && (v2m - v3m) < TAU) {
                unsigned int idx = atomicAdd(flags, 1u);
                if (idx < CAP) flags[1 + idx] = (unsigned int)r;
            }
            const int c0 = 2 * e0, c1 = c0 + 1;
            const float o0 = (c0 == e1m) ? w1 : (c0 == e2m) ? w2 : 0.0f;
            const float o1 = (c1 == e1m) ? w1 : (c1 == e2m) ? w2 : 0.0f;
            *(float2*)(out + (size_t)r * NEXP + c0) = make_float2(o0, o1);
        }
    }
}

// fp64 re-solve of flagged rows: one 64-lane block per row, lane = expert.
__global__ void gate_repair(const float* __restrict__ x, const float* __restrict__ W,
                            const float* __restrict__ b, const float* __restrict__ noise,
                            float* __restrict__ out, const unsigned int* __restrict__ flags,
                            int D) {
    unsigned int cnt = flags[0];
    if (cnt > CAP) cnt = CAP;
    if (blockIdx.x >= cnt) return;
    const int r = (int)flags[1 + blockIdx.x];
    const int e = threadIdx.x;  // 0..63

    const float* xr = x + (size_t)r * D;
    const float* wr = W + (size_t)e * D;
    double s = 0.0;
    for (int d0 = 0; d0 < D; d0 += 4) {
        float4 xv = *(const float4*)(xr + d0);
        float4 wv = *(const float4*)(wr + d0);
        s += (double)xv.x * (double)wv.x;
        s += (double)xv.y * (double)wv.y;
        s += (double)xv.z * (double)wv.z;
        s += (double)xv.w * (double)wv.w;
    }
    const float clean = (float)s + b[e];
    const float v     = clean + noise[(size_t)r * NEXP + e];

    float v1 = v, v2 = -1e30f; int e1 = e, e2 = 99;
    for (int d = 1; d < 64; d <<= 1) {
        float ov1 = __shfl_xor(v1, d); int oe1 = __shfl_xor(e1, d);
        float ov2 = __shfl_xor(v2, d); int oe2 = __shfl_xor(e2, d);
        bool  aw  = beats(v1, e1, ov1, oe1);
        float a1v = aw ? v1 : ov1; int a1e = aw ? e1 : oe1;
        float b1v = aw ? ov1 : v1; int b1e = aw ? oe1 : e1;
        float a2v = aw ? v2 : ov2; int a2e = aw ? e2 : oe2;
        bool  s2  = beats(a2v, a2e, b1v, b1e);
        v1 = a1v; e1 = a1e;
        v2 = s2 ? a2v : b1v; e2 = s2 ? a2e : b1e;
    }
    const float t   = __expf(v2 - v1);
    const float inv = 1.0f / (1.0f + t);
    out[(size_t)r * NEXP + e] = (e == e1) ? inv : (e == e2) ? t * inv : 0.0f;
}

extern "C" void kernel_launch(void* const* d_in, const int* in_sizes, int n_in,
                              void* d_out, int out_size, void* d_ws, size_t ws_size,
                              hipStream_t stream) {
    const float* x     = (const float*)d_in[0];
    const float* W     = (const float*)d_in[1];
    const float* b     = (const float*)d_in[2];
    const float* noise = (const float*)d_in[3];
    float* out = (float*)d_out;

    const int E = in_sizes[2];       // 64
    const int D = in_sizes[1] / E;   // 1024
    const int N = in_sizes[0] / D;   // 131072

    unsigned int* flags = (unsigned int*)d_ws;
    char* wsW = (char*)d_ws + WS_W_OFF;

    convW_kernel<<<dim3(E), dim3(128), 0, stream>>>(W, wsW);
    hipMemsetAsync(d_ws, 0, sizeof(unsigned int), stream);
    gate_mfma<<<dim3(N / TILE_M), dim3(BLOCK), 0, stream>>>(x, b, noise, wsW, out, flags);
    gate_repair<<<dim3(CAP), dim3(64), 0, stream>>>(x, W, b, noise, out, flags, D);
}

// Round 13
// 209.982 us; speedup vs baseline: 1.0976x; 1.0976x over previous
//
#include <hip/hip_runtime.h>
#include <math.h>

// NoisyTopKGating: out[N,64] = scatter(softmax(top2(x@W^T + b + noise)))
// N=131072, D=1024, E=64, K=2, NOISE_STD=1.0
//
// Round 13 = Round 9 (best, 204.8us) + NON-TEMPORAL policy on streamed-once
// buffers (single variable). R4-R12 falsified sync structure, pipeline depth,
// run length, stream independence -- x stays at ~2.9 TB/s with default cache
// policy while same-chip fills do 6.7. Remaining mechanism: x (512MB = 2x L3)
// allocates+evicts on every line with zero reuse -> L3/L2 fill machinery on
// the read path. This round: x staged with global_load_lds aux=2 (nt), noise
// via __builtin_nontemporal_load, out via nontemporal stores. W image keeps
// default policy (it IS reused from L2). Everything else byte-identical to
// R9: 512B runs, TILE_M=64, 2 blocks/CU, W reg-preload, counted vmcnt(8),
// dual barrier, k-phase rotation, quad top-k epilogue, fp64 repair net.

#define NEXP   64
#define BLOCK  256
#define TILE_M 64
#define DFIX   1024
#define KCF    128       // K floats per chunk -> 512 B per row per visit
#define NCH    8         // DFIX / KCF
#define XCHB   32768     // x chunk: 64 rows x 512 B
#define TAU    1e-3f
#define CAP    4096
#define WS_W_OFF 32768   // frag-major W image at d_ws + 32 KB

typedef __attribute__((ext_vector_type(8)))  short bf16x8;
typedef __attribute__((ext_vector_type(16))) float f32x16;
typedef __attribute__((ext_vector_type(4)))  float f32x4v;

__device__ __forceinline__ bool beats(float v, int e, float vo, int eo) {
    // jax.lax.top_k ordering: higher value wins, lower index on tie
    return (v > vo) || (v == vo && e < eo);
}

// Split two fp32 into packed bf16-hi pair and bf16-lo (residual) pair, by truncation.
__device__ __forceinline__ void split2(float f0, float f1, unsigned int& hi, unsigned int& lo) {
    unsigned int u0 = __float_as_uint(f0), u1 = __float_as_uint(f1);
    unsigned int h0 = u0 & 0xFFFF0000u,  h1 = u1 & 0xFFFF0000u;
    float l0 = f0 - __uint_as_float(h0);
    float l1 = f1 - __uint_as_float(h1);
    hi = (u0 >> 16) | h1;
    lo = (__float_as_uint(l0) >> 16) | (__float_as_uint(l1) & 0xFFFF0000u);
}

// aux=2 -> nt (non-temporal / streaming): evict-first, minimal cache pollution.
__device__ __forceinline__ void gl_lds16_nt(const void* g, void* l) {
    __builtin_amdgcn_global_load_lds((const __attribute__((address_space(1))) void*)g,
                                     (__attribute__((address_space(3))) void*)l,
                                     16, 0, 2);
}

// W (64x1024 fp32) -> frag-major bf16 hi/lo image (256 KB):
// frag f = kk*4 + g*2 + h (kk = k-step 0..63, g = expert-half, h: 0=hi 1=lo),
// lane l of frag f holds W[e = g*32 + (l&31)][k = kk*16 + (l>>5)*8 .. +8] (16B).
__global__ void convW_kernel(const float* __restrict__ W, char* __restrict__ wsW) {
    const int e = blockIdx.x;        // 0..63
    const int t = threadIdx.x;       // 0..127 = global k-octet
    const float* wp = W + e * DFIX + t * 8;
    float4 a  = *(const float4*)wp;
    float4 bq = *(const float4*)(wp + 4);
    unsigned int h[4], l[4];
    split2(a.x,  a.y,  h[0], l[0]);
    split2(a.z,  a.w,  h[1], l[1]);
    split2(bq.x, bq.y, h[2], l[2]);
    split2(bq.z, bq.w, h[3], l[3]);
    const int kk   = t >> 1;         // k-step 0..63
    const int lh   = t & 1;          // k-octet within k-step
    const int lane = lh * 32 + (e & 31);
    const int g    = e >> 5;
    char* base = wsW + (size_t)(kk * 4 + g * 2) * 1024 + lane * 16;
    *(uint4*)(base)        = make_uint4(h[0], h[1], h[2], h[3]);  // h=0 (hi)
    *(uint4*)(base + 1024) = make_uint4(l[0], l[1], l[2], l[3]);  // h=1 (lo)
}

__global__ __launch_bounds__(BLOCK, 2)
void gate_mfma(const float* __restrict__ x, const float* __restrict__ bvec,
               const float* __restrict__ noise, const char* __restrict__ wsW,
               float* __restrict__ out, unsigned int* __restrict__ flags) {
    __shared__ __align__(16) char lds[2 * XCHB];   // 64 KB -> 2 blocks/CU

    const int tid  = threadIdx.x;
    const int wv   = tid >> 6;       // wave 0..3
    const int lane = tid & 63;
    const int e0   = lane & 31;
    const int lh   = lane >> 5;      // k-octet half selector
    const int rg   = wv & 1;         // row group: rows rg*32..+32
    const int cg   = wv >> 1;        // col group: experts cg*32..+32
    const int blkRow0 = blockIdx.x * TILE_M;
    const int rowL  = rg * 32 + e0;  // this lane's A row within tile (0..63)
    const int phase = blockIdx.x & (NCH - 1);   // k-phase rotation (R7)

    f32x16 acc = (f32x16)0.0f;       // 32 rows x 32 experts per wave

    // Stage GLOBAL chunk gc (512B per row) into buffer buf: 8 gl_lds16 per
    // wave; LDS slot (row, seg) holds global seg (seg ^ (row&31)) of that row
    // (inverse-swizzled source, linear dest; XOR is the involution).
    auto STAGE = [&](int gc, int buf) {
        char* xb = lds + buf * XCHB;
        #pragma unroll
        for (int j = 0; j < 8; j++) {
            const int s   = j * 256 + wv * 64 + lane;   // 16B-slot id 0..2047
            const int row = s >> 5;
            const int seg = (s & 31) ^ (row & 31);
            const char* gp = (const char*)(x + (size_t)(blkRow0 + row) * DFIX)
                             + (size_t)gc * 512 + seg * 16;
            gl_lds16_nt(gp, xb + (size_t)(j * 256 + wv * 64) * 16);  // +lane*16 by HW
        }
    };

    // Per-chunk W fragments (this wave's col group, hi+lo, 8 ksteps) -> regs.
    // Issued BEFORE the next STAGE so in-order vmcnt retirement keeps the
    // hand count exact: vmcnt(8) == stage(c)+W(c) done, stage(c+1) in flight.
    int4 wreg[16];
    auto WPRE = [&](int gc) {
        const char* base = wsW + (size_t)(gc * 32 + cg * 2) * 1024 + lane * 16;
        #pragma unroll
        for (int ks = 0; ks < 8; ks++) {
            wreg[ks * 2 + 0] = *(const int4*)(base + (ks * 4 + 0) * 1024);  // hi
            wreg[ks * 2 + 1] = *(const int4*)(base + (ks * 4 + 1) * 1024);  // lo
        }
    };

    auto COMPUTE = [&](int buf) {
        const char* xb = lds + buf * XCHB;
        #pragma unroll
        for (int ks = 0; ks < 8; ks++) {
            const int g0 = ks * 4 + lh * 2;             // global seg wanted
            const int4 xq0 = *(const int4*)(xb + rowL * 512 + ((g0    ) ^ (rowL & 31)) * 16);
            const int4 xq1 = *(const int4*)(xb + rowL * 512 + ((g0 + 1) ^ (rowL & 31)) * 16);
            const float4 xa = *(const float4*)&xq0;
            const float4 xc = *(const float4*)&xq1;
            union { bf16x8 v; unsigned int u[4]; } ah, al;
            split2(xa.x, xa.y, ah.u[0], al.u[0]);
            split2(xa.z, xa.w, ah.u[1], al.u[1]);
            split2(xc.x, xc.y, ah.u[2], al.u[2]);
            split2(xc.z, xc.w, ah.u[3], al.u[3]);
            union { bf16x8 v; int4 q; } bh, bl;
            bh.q = wreg[ks * 2 + 0];
            bl.q = wreg[ks * 2 + 1];
            acc = __builtin_amdgcn_mfma_f32_32x32x16_bf16(ah.v, bh.v, acc, 0, 0, 0);
            acc = __builtin_amdgcn_mfma_f32_32x32x16_bf16(ah.v, bl.v, acc, 0, 0, 0);
            acc = __builtin_amdgcn_mfma_f32_32x32x16_bf16(al.v, bh.v, acc, 0, 0, 0);
        }
    };

    // Pipeline: NBUF=2, dual barrier per chunk; counted vmcnt never 0 in-loop.
    STAGE(phase, 0);
    #pragma unroll 1
    for (int c = 0; c < NCH - 1; c++) {
        WPRE((c + phase) & (NCH - 1));
        STAGE((c + 1 + phase) & (NCH - 1), (c + 1) & 1);
        asm volatile("s_waitcnt vmcnt(8)" ::: "memory");
        __builtin_amdgcn_s_barrier();
        __builtin_amdgcn_sched_barrier(0);
        COMPUTE(c & 1);
        __builtin_amdgcn_s_barrier();   // all waves done reading buf (c&1)
    }
    WPRE((NCH - 1 + phase) & (NCH - 1));
    asm volatile("s_waitcnt vmcnt(0)" ::: "memory");
    __builtin_amdgcn_s_barrier();
    __builtin_amdgcn_sched_barrier(0);
    COMPUTE((NCH - 1) & 1);

    // ---- Epilogue (R9-proven): logits -> LDS (swizzled 16B slots in buf0,
    // disjoint from buf1 read by final COMPUTE), __syncthreads, quad top-k. ----
    // C layout (verified m74/m101 + rounds 3-12): col = lane&31,
    // row = (reg&3) + 8*(reg>>2) + 4*lh.
    const float bb = bvec[cg * 32 + e0];
    #pragma unroll
    for (int q = 0; q < 4; q++) {
        #pragma unroll
        for (int j = 0; j < 4; j++) {
            const int reg = q * 4 + j;
            const int rl  = rg * 32 + j + 8 * q + 4 * lh;   // row local 0..63
            const int r   = blkRow0 + rl;
            const int col = cg * 32 + e0;
            const float nv = __builtin_nontemporal_load(&noise[(size_t)r * NEXP + col]);
            const float v  = (acc[reg] + bb) + nv;          // ref order: (dot+b)+noise
            const int slot = (col >> 2) ^ (rl & 15);        // bank-spread swizzle
            *(float*)(lds + rl * 256 + slot * 16 + (col & 3) * 4) = v;
        }
    }
    __syncthreads();   // ds_write -> cross-wave ds_read handoff (R8 lesson)

    {
        const int trow = tid >> 2;
        const int qd   = tid & 3;
        float v1 = -1e30f, v2 = -1e30f, v3 = -1e30f;
        int   e1 = 99, e2 = 99;
        #pragma unroll
        for (int i = 0; i < 4; i++) {
            const int slot = (qd * 4 + i) ^ (trow & 15);
            const float4 f = *(const float4*)(lds + trow * 256 + slot * 16);
            #pragma unroll
            for (int m = 0; m < 4; m++) {
                const float v = (m == 0) ? f.x : (m == 1) ? f.y : (m == 2) ? f.z : f.w;
                const int   e = qd * 16 + i * 4 + m;
                if (beats(v, e, v1, e1))      { v3 = v2; v2 = v1; e2 = e1; v1 = v; e1 = e; }
                else if (beats(v, e, v2, e2)) { v3 = v2; v2 = v;  e2 = e; }
                else                          { v3 = fmaxf(v3, v); }
            }
        }
        #pragma unroll
        for (int d = 1; d < 4; d <<= 1) {
            float ov1 = __shfl_xor(v1, d); int oe1 = __shfl_xor(e1, d);
            float ov2 = __shfl_xor(v2, d); int oe2 = __shfl_xor(e2, d);
            float ov3 = __shfl_xor(v3, d);
            bool  aw  = beats(v1, e1, ov1, oe1);
            float a1v = aw ? v1 : ov1; int a1e = aw ? e1 : oe1;
            float b1v = aw ? ov1 : v1; int b1e = aw ? oe1 : e1;
            float a2v = aw ? v2 : ov2; int a2e = aw ? e2 : oe2;
            float b2v = aw ? ov2 : v2;
            float a3v = aw ? v3 : ov3;
            bool  s2  = beats(a2v, a2e, b1v, b1e);
            v1 = a1v; e1 = a1e;
            v2 = s2 ? a2v : b1v; e2 = s2 ? a2e : b1e;
            v3 = s2 ? fmaxf(a3v, b1v) : fmaxf(a2v, b2v);
        }
        const float t   = __expf(v2 - v1);
        const float inv = 1.0f / (1.0f + t);
        const float w1  = inv, w2 = t * inv;
        const int   r   = blkRow0 + trow;

        if (qd == 0 && (v2 - v3) < TAU) {
            unsigned int idx = atomicAdd(flags, 1u);
            if (idx < CAP) flags[1 + idx] = (unsigned int)r;
        }
        float* op = out + (size_t)r * NEXP + qd * 16;
        #pragma unroll
        for (int i = 0; i < 4; i++) {
            float o[4];
            #pragma unroll
            for (int m = 0; m < 4; m++) {
                const int e = qd * 16 + i * 4 + m;
                o[m] = (e == e1) ? w1 : (e == e2) ? w2 : 0.0f;
            }
            f32x4v ov = {o[0], o[1], o[2], o[3]};
            __builtin_nontemporal_store(ov, (f32x4v*)(op + i * 4));  // streamed-once
        }
    }
}

// fp64 re-solve of flagged rows: one 64-lane block per row, lane = expert.
__global__ void gate_repair(const float* __restrict__ x, const float* __restrict__ W,
                            const float* __restrict__ b, const float* __restrict__ noise,
                            float* __restrict__ out, const unsigned int* __restrict__ flags,
                            int D) {
    unsigned int cnt = flags[0];
    if (cnt > CAP) cnt = CAP;
    if (blockIdx.x >= cnt) return;
    const int r = (int)flags[1 + blockIdx.x];
    const int e = threadIdx.x;  // 0..63

    const float* xr = x + (size_t)r * D;
    const float* wr = W + (size_t)e * D;
    double s = 0.0;
    for (int d0 = 0; d0 < D; d0 += 4) {
        float4 xv = *(const float4*)(xr + d0);
        float4 wv = *(const float4*)(wr + d0);
        s += (double)xv.x * (double)wv.x;
        s += (double)xv.y * (double)wv.y;
        s += (double)xv.z * (double)wv.z;
        s += (double)xv.w * (double)wv.w;
    }
    const float clean = (float)s + b[e];
    const float v     = clean + noise[(size_t)r * NEXP + e];

    float v1 = v, v2 = -1e30f; int e1 = e, e2 = 99;
    for (int d = 1; d < 64; d <<= 1) {
        float ov1 = __shfl_xor(v1, d); int oe1 = __shfl_xor(e1, d);
        float ov2 = __shfl_xor(v2, d); int oe2 = __shfl_xor(e2, d);
        bool  aw  = beats(v1, e1, ov1, oe1);
        float a1v = aw ? v1 : ov1; int a1e = aw ? e1 : oe1;
        float b1v = aw ? ov1 : v1; int b1e = aw ? oe1 : e1;
        float a2v = aw ? v2 : ov2; int a2e = aw ? e2 : oe2;
        bool  s2  = beats(a2v, a2e, b1v, b1e);
        v1 = a1v; e1 = a1e;
        v2 = s2 ? a2v : b1v; e2 = s2 ? a2e : b1e;
    }
    const float t   = __expf(v2 - v1);
    const float inv = 1.0f / (1.0f + t);
    out[(size_t)r * NEXP + e] = (e == e1) ? inv : (e == e2) ? t * inv : 0.0f;
}

extern "C" void kernel_launch(void* const* d_in, const int* in_sizes, int n_in,
                              void* d_out, int out_size, void* d_ws, size_t ws_size,
                              hipStream_t stream) {
    const float* x     = (const float*)d_in[0];
    const float* W     = (const float*)d_in[1];
    const float* b     = (const float*)d_in[2];
    const float* noise = (const float*)d_in[3];
    float* out = (float*)d_out;

    const int E = in_sizes[2];       // 64
    const int D = in_sizes[1] / E;   // 1024
    const int N = in_sizes[0] / D;   // 131072

    unsigned int* flags = (unsigned int*)d_ws;
    char* wsW = (char*)d_ws + WS_W_OFF;

    convW_kernel<<<dim3(E), dim3(128), 0, stream>>>(W, wsW);
    hipMemsetAsync(d_ws, 0, sizeof(unsigned int), stream);
    gate_mfma<<<dim3(N / TILE_M), dim3(BLOCK), 0, stream>>>(x, b, noise, wsW, out, flags);
    gate_repair<<<dim3(CAP), dim3(64), 0, stream>>>(x, W, b, noise, out, flags, D);
}

// Round 14
// 202.757 us; speedup vs baseline: 1.1367x; 1.0356x over previous
//
#include <hip/hip_runtime.h>
#include <math.h>

// NoisyTopKGating: out[N,64] = scatter(softmax(top2(x@W^T + b + noise)))
// N=131072, D=1024, E=64, K=2, NOISE_STD=1.0
//
// Round 14 = Round 9 (best, 204.8us; NT reverted — R13 showed neutral/negative)
// + overhead trims: flags[0] zeroed inside convW (memset dispatch dropped),
// repair grid-strided at 1024 blocks. Conclusion from R4-R13 falsification
// ladder: the x-stream is pinned at ~2.9-3.0 TB/s across ALL source-level
// structures; all measured evidence (m13 copy read-side ~3.15 TB/s, fills
// 6.7 TB/s write-only) supports a ~3.0-3.15 TB/s streaming-READ ceiling on
// this part. 576MB total traffic / ~3 TB/s ~= 192us + ~8us overhead = floor.
// Structure: 512B runs, TILE_M=64, 2 blocks/CU, W reg-preload from L2-resident
// frag-major image, counted vmcnt(8) (never 0 in-loop), dual barrier, k-phase
// rotation, quad top-k epilogue; fp64 repair net for gap(#2,#3) < TAU.

#define NEXP   64
#define BLOCK  256
#define TILE_M 64
#define DFIX   1024
#define KCF    128       // K floats per chunk -> 512 B per row per visit
#define NCH    8         // DFIX / KCF
#define XCHB   32768     // x chunk: 64 rows x 512 B
#define TAU    1e-3f
#define CAP    4096
#define RGRID  1024      // repair grid (grid-strided over flagged rows)
#define WS_W_OFF 32768   // frag-major W image at d_ws + 32 KB

typedef __attribute__((ext_vector_type(8)))  short bf16x8;
typedef __attribute__((ext_vector_type(16))) float f32x16;

__device__ __forceinline__ bool beats(float v, int e, float vo, int eo) {
    // jax.lax.top_k ordering: higher value wins, lower index on tie
    return (v > vo) || (v == vo && e < eo);
}

// Split two fp32 into packed bf16-hi pair and bf16-lo (residual) pair, by truncation.
__device__ __forceinline__ void split2(float f0, float f1, unsigned int& hi, unsigned int& lo) {
    unsigned int u0 = __float_as_uint(f0), u1 = __float_as_uint(f1);
    unsigned int h0 = u0 & 0xFFFF0000u,  h1 = u1 & 0xFFFF0000u;
    float l0 = f0 - __uint_as_float(h0);
    float l1 = f1 - __uint_as_float(h1);
    hi = (u0 >> 16) | h1;
    lo = (__float_as_uint(l0) >> 16) | (__float_as_uint(l1) & 0xFFFF0000u);
}

__device__ __forceinline__ void gl_lds16(const void* g, void* l) {
    __builtin_amdgcn_global_load_lds((const __attribute__((address_space(1))) void*)g,
                                     (__attribute__((address_space(3))) void*)l,
                                     16, 0, 0);
}

// W (64x1024 fp32) -> frag-major bf16 hi/lo image (256 KB). Also zeroes the
// repair counter (replaces the memset dispatch; stream order makes it visible
// to gate_mfma, and each graph replay re-zeroes deterministically).
__global__ void convW_kernel(const float* __restrict__ W, char* __restrict__ wsW,
                             unsigned int* __restrict__ flags) {
    if (blockIdx.x == 0 && threadIdx.x == 0) flags[0] = 0u;
    const int e = blockIdx.x;        // 0..63
    const int t = threadIdx.x;       // 0..127 = global k-octet
    const float* wp = W + e * DFIX + t * 8;
    float4 a  = *(const float4*)wp;
    float4 bq = *(const float4*)(wp + 4);
    unsigned int h[4], l[4];
    split2(a.x,  a.y,  h[0], l[0]);
    split2(a.z,  a.w,  h[1], l[1]);
    split2(bq.x, bq.y, h[2], l[2]);
    split2(bq.z, bq.w, h[3], l[3]);
    const int kk   = t >> 1;         // k-step 0..63
    const int lh   = t & 1;          // k-octet within k-step
    const int lane = lh * 32 + (e & 31);
    const int g    = e >> 5;
    char* base = wsW + (size_t)(kk * 4 + g * 2) * 1024 + lane * 16;
    *(uint4*)(base)        = make_uint4(h[0], h[1], h[2], h[3]);  // h=0 (hi)
    *(uint4*)(base + 1024) = make_uint4(l[0], l[1], l[2], l[3]);  // h=1 (lo)
}

__global__ __launch_bounds__(BLOCK, 2)
void gate_mfma(const float* __restrict__ x, const float* __restrict__ bvec,
               const float* __restrict__ noise, const char* __restrict__ wsW,
               float* __restrict__ out, unsigned int* __restrict__ flags) {
    __shared__ __align__(16) char lds[2 * XCHB];   // 64 KB -> 2 blocks/CU

    const int tid  = threadIdx.x;
    const int wv   = tid >> 6;       // wave 0..3
    const int lane = tid & 63;
    const int e0   = lane & 31;
    const int lh   = lane >> 5;      // k-octet half selector
    const int rg   = wv & 1;         // row group: rows rg*32..+32
    const int cg   = wv >> 1;        // col group: experts cg*32..+32
    const int blkRow0 = blockIdx.x * TILE_M;
    const int rowL  = rg * 32 + e0;  // this lane's A row within tile (0..63)
    const int phase = blockIdx.x & (NCH - 1);   // k-phase rotation (R7)

    f32x16 acc = (f32x16)0.0f;       // 32 rows x 32 experts per wave

    // Stage GLOBAL chunk gc (512B per row) into buffer buf: 8 gl_lds16 per
    // wave; LDS slot (row, seg) holds global seg (seg ^ (row&31)) of that row
    // (inverse-swizzled source, linear dest; XOR is the involution).
    auto STAGE = [&](int gc, int buf) {
        char* xb = lds + buf * XCHB;
        #pragma unroll
        for (int j = 0; j < 8; j++) {
            const int s   = j * 256 + wv * 64 + lane;   // 16B-slot id 0..2047
            const int row = s >> 5;
            const int seg = (s & 31) ^ (row & 31);
            const char* gp = (const char*)(x + (size_t)(blkRow0 + row) * DFIX)
                             + (size_t)gc * 512 + seg * 16;
            gl_lds16(gp, xb + (size_t)(j * 256 + wv * 64) * 16);  // +lane*16 by HW
        }
    };

    // Per-chunk W fragments (this wave's col group, hi+lo, 8 ksteps) -> regs.
    // Issued BEFORE the next STAGE so in-order vmcnt retirement keeps the
    // hand count exact: vmcnt(8) == stage(c)+W(c) done, stage(c+1) in flight.
    int4 wreg[16];
    auto WPRE = [&](int gc) {
        const char* base = wsW + (size_t)(gc * 32 + cg * 2) * 1024 + lane * 16;
        #pragma unroll
        for (int ks = 0; ks < 8; ks++) {
            wreg[ks * 2 + 0] = *(const int4*)(base + (ks * 4 + 0) * 1024);  // hi
            wreg[ks * 2 + 1] = *(const int4*)(base + (ks * 4 + 1) * 1024);  // lo
        }
    };

    auto COMPUTE = [&](int buf) {
        const char* xb = lds + buf * XCHB;
        #pragma unroll
        for (int ks = 0; ks < 8; ks++) {
            const int g0 = ks * 4 + lh * 2;             // global seg wanted
            const int4 xq0 = *(const int4*)(xb + rowL * 512 + ((g0    ) ^ (rowL & 31)) * 16);
            const int4 xq1 = *(const int4*)(xb + rowL * 512 + ((g0 + 1) ^ (rowL & 31)) * 16);
            const float4 xa = *(const float4*)&xq0;
            const float4 xc = *(const float4*)&xq1;
            union { bf16x8 v; unsigned int u[4]; } ah, al;
            split2(xa.x, xa.y, ah.u[0], al.u[0]);
            split2(xa.z, xa.w, ah.u[1], al.u[1]);
            split2(xc.x, xc.y, ah.u[2], al.u[2]);
            split2(xc.z, xc.w, ah.u[3], al.u[3]);
            union { bf16x8 v; int4 q; } bh, bl;
            bh.q = wreg[ks * 2 + 0];
            bl.q = wreg[ks * 2 + 1];
            acc = __builtin_amdgcn_mfma_f32_32x32x16_bf16(ah.v, bh.v, acc, 0, 0, 0);
            acc = __builtin_amdgcn_mfma_f32_32x32x16_bf16(ah.v, bl.v, acc, 0, 0, 0);
            acc = __builtin_amdgcn_mfma_f32_32x32x16_bf16(al.v, bh.v, acc, 0, 0, 0);
        }
    };

    // Pipeline: NBUF=2, dual barrier per chunk; counted vmcnt never 0 in-loop.
    STAGE(phase, 0);
    #pragma unroll 1
    for (int c = 0; c < NCH - 1; c++) {
        WPRE((c + phase) & (NCH - 1));
        STAGE((c + 1 + phase) & (NCH - 1), (c + 1) & 1);
        asm volatile("s_waitcnt vmcnt(8)" ::: "memory");
        __builtin_amdgcn_s_barrier();
        __builtin_amdgcn_sched_barrier(0);
        COMPUTE(c & 1);
        __builtin_amdgcn_s_barrier();   // all waves done reading buf (c&1)
    }
    WPRE((NCH - 1 + phase) & (NCH - 1));
    asm volatile("s_waitcnt vmcnt(0)" ::: "memory");
    __builtin_amdgcn_s_barrier();
    __builtin_amdgcn_sched_barrier(0);
    COMPUTE((NCH - 1) & 1);

    // ---- Epilogue (R9-proven): logits -> LDS (swizzled 16B slots in buf0,
    // disjoint from buf1 read by final COMPUTE), __syncthreads, quad top-k. ----
    // C layout (verified m74/m101 + rounds 3-13): col = lane&31,
    // row = (reg&3) + 8*(reg>>2) + 4*lh.
    const float bb = bvec[cg * 32 + e0];
    #pragma unroll
    for (int q = 0; q < 4; q++) {
        #pragma unroll
        for (int j = 0; j < 4; j++) {
            const int reg = q * 4 + j;
            const int rl  = rg * 32 + j + 8 * q + 4 * lh;   // row local 0..63
            const int r   = blkRow0 + rl;
            const int col = cg * 32 + e0;
            const float v = (acc[reg] + bb) + noise[(size_t)r * NEXP + col];
            const int slot = (col >> 2) ^ (rl & 15);        // bank-spread swizzle
            *(float*)(lds + rl * 256 + slot * 16 + (col & 3) * 4) = v;
        }
    }
    __syncthreads();   // ds_write -> cross-wave ds_read handoff (R8 lesson)

    {
        const int trow = tid >> 2;
        const int qd   = tid & 3;
        float v1 = -1e30f, v2 = -1e30f, v3 = -1e30f;
        int   e1 = 99, e2 = 99;
        #pragma unroll
        for (int i = 0; i < 4; i++) {
            const int slot = (qd * 4 + i) ^ (trow & 15);
            const float4 f = *(const float4*)(lds + trow * 256 + slot * 16);
            #pragma unroll
            for (int m = 0; m < 4; m++) {
                const float v = (m == 0) ? f.x : (m == 1) ? f.y : (m == 2) ? f.z : f.w;
                const int   e = qd * 16 + i * 4 + m;
                if (beats(v, e, v1, e1))      { v3 = v2; v2 = v1; e2 = e1; v1 = v; e1 = e; }
                else if (beats(v, e, v2, e2)) { v3 = v2; v2 = v;  e2 = e; }
                else                          { v3 = fmaxf(v3, v); }
            }
        }
        #pragma unroll
        for (int d = 1; d < 4; d <<= 1) {
            float ov1 = __shfl_xor(v1, d); int oe1 = __shfl_xor(e1, d);
            float ov2 = __shfl_xor(v2, d); int oe2 = __shfl_xor(e2, d);
            float ov3 = __shfl_xor(v3, d);
            bool  aw  = beats(v1, e1, ov1, oe1);
            float a1v = aw ? v1 : ov1; int a1e = aw ? e1 : oe1;
            float b1v = aw ? ov1 : v1; int b1e = aw ? oe1 : e1;
            float a2v = aw ? v2 : ov2; int a2e = aw ? e2 : oe2;
            float b2v = aw ? ov2 : v2;
            float a3v = aw ? v3 : ov3;
            bool  s2  = beats(a2v, a2e, b1v, b1e);
            v1 = a1v; e1 = a1e;
            v2 = s2 ? a2v : b1v; e2 = s2 ? a2e : b1e;
            v3 = s2 ? fmaxf(a3v, b1v) : fmaxf(a2v, b2v);
        }
        const float t   = __expf(v2 - v1);
        const float inv = 1.0f / (1.0f + t);
        const float w1  = inv, w2 = t * inv;
        const int   r   = blkRow0 + trow;

        if (qd == 0 && (v2 - v3) < TAU) {
            unsigned int idx = atomicAdd(flags, 1u);
            if (idx < CAP) flags[1 + idx] = (unsigned int)r;
        }
        float* op = out + (size_t)r * NEXP + qd * 16;
        #pragma unroll
        for (int i = 0; i < 4; i++) {
            float o[4];
            #pragma unroll
            for (int m = 0; m < 4; m++) {
                const int e = qd * 16 + i * 4 + m;
                o[m] = (e == e1) ? w1 : (e == e2) ? w2 : 0.0f;
            }
            *(float4*)(op + i * 4) = make_float4(o[0], o[1], o[2], o[3]);
        }
    }
}

// fp64 re-solve of flagged rows: one 64-lane block per row, grid-strided.
__global__ void gate_repair(const float* __restrict__ x, const float* __restrict__ W,
                            const float* __restrict__ b, const float* __restrict__ noise,
                            float* __restrict__ out, const unsigned int* __restrict__ flags,
                            int D) {
    unsigned int cnt = flags[0];
    if (cnt > CAP) cnt = CAP;
    for (unsigned int w = blockIdx.x; w < cnt; w += RGRID) {
        const int r = (int)flags[1 + w];
        const int e = threadIdx.x;  // 0..63

        const float* xr = x + (size_t)r * D;
        const float* wr = W + (size_t)e * D;
        double s = 0.0;
        for (int d0 = 0; d0 < D; d0 += 4) {
            float4 xv = *(const float4*)(xr + d0);
            float4 wv = *(const float4*)(wr + d0);
            s += (double)xv.x * (double)wv.x;
            s += (double)xv.y * (double)wv.y;
            s += (double)xv.z * (double)wv.z;
            s += (double)xv.w * (double)wv.w;
        }
        const float clean = (float)s + b[e];
        const float v     = clean + noise[(size_t)r * NEXP + e];

        float v1 = v, v2 = -1e30f; int e1 = e, e2 = 99;
        for (int d = 1; d < 64; d <<= 1) {
            float ov1 = __shfl_xor(v1, d); int oe1 = __shfl_xor(e1, d);
            float ov2 = __shfl_xor(v2, d); int oe2 = __shfl_xor(e2, d);
            bool  aw  = beats(v1, e1, ov1, oe1);
            float a1v = aw ? v1 : ov1; int a1e = aw ? e1 : oe1;
            float b1v = aw ? ov1 : v1; int b1e = aw ? oe1 : e1;
            float a2v = aw ? v2 : ov2; int a2e = aw ? e2 : oe2;
            bool  s2  = beats(a2v, a2e, b1v, b1e);
            v1 = a1v; e1 = a1e;
            v2 = s2 ? a2v : b1v; e2 = s2 ? a2e : b1e;
        }
        const float t   = __expf(v2 - v1);
        const float inv = 1.0f / (1.0f + t);
        out[(size_t)r * NEXP + e] = (e == e1) ? inv : (e == e2) ? t * inv : 0.0f;
    }
}

extern "C" void kernel_launch(void* const* d_in, const int* in_sizes, int n_in,
                              void* d_out, int out_size, void* d_ws, size_t ws_size,
                              hipStream_t stream) {
    const float* x     = (const float*)d_in[0];
    const float* W     = (const float*)d_in[1];
    const float* b     = (const float*)d_in[2];
    const float* noise = (const float*)d_in[3];
    float* out = (float*)d_out;

    const int E = in_sizes[2];       // 64
    const int D = in_sizes[1] / E;   // 1024
    const int N = in_sizes[0] / D;   // 131072

    unsigned int* flags = (unsigned int*)d_ws;
    char* wsW = (char*)d_ws + WS_W_OFF;

    convW_kernel<<<dim3(E), dim3(128), 0, stream>>>(W, wsW, flags);
    gate_mfma<<<dim3(N / TILE_M), dim3(BLOCK), 0, stream>>>(x, b, noise, wsW, out, flags);
    gate_repair<<<dim3(RGRID), dim3(64), 0, stream>>>(x, W, b, noise, out, flags, D);
}